// Round 12
// baseline (118.435 us; speedup 1.0000x reference)
//
#include <hip/hip_runtime.h>
#include <hip/hip_fp16.h>

// KANLayer: out = (relu(x[:,:,None]*W1+b1) . W2 + b2) @ Wc^T + bc
// B=16384, D=256, H=64, O=256.
// v8: lane<->batch-row mapping. Weights are wave-UNIFORM (s_load/SGPR, zero
//     VGPR/LDS cost); thread owns x[b][d0..d0+15] (one 64B line). u written
//     to __device__ buffer in MFMA-A-fragment order (coalesced), so the GEMM
//     kernel (kan_p2) runs with zero LDS / zero barriers.
#define B_N 16384
#define D_N 256
#define H_N 64
#define O_N 256

typedef unsigned int u32;
typedef unsigned short u16;
typedef _Float16 f16;
typedef __attribute__((ext_vector_type(2))) _Float16 f16x2;
typedef __attribute__((ext_vector_type(8))) _Float16 f16x8;
typedef __attribute__((ext_vector_type(4))) float f32x4;
typedef __attribute__((ext_vector_type(4))) u32 uint4v;
typedef __attribute__((ext_vector_type(4))) u16 u16x4;

// Packed params, rewritten by prep() every launch (idempotent -> graph-safe).
__device__ u32 g_Wp [D_N * 32];  // half2{W1[d][2j],W1[d][2j+1]}
__device__ u32 g_Bp [D_N * 32];  // half2 b1
__device__ u32 g_W2p[D_N * 32];  // half2 W2
__device__ __attribute__((aligned(16))) u16 g_Wch[O_N * D_N];  // f16(Wc)
// u in MFMA-A-fragment order: [b>>4][kb=d>>3][b&15][d&7], 8MB (BSS)
__device__ __attribute__((aligned(16))) u16 g_Uf[B_N * D_N];

union HU { f16 h; u16 b; };

static __device__ __forceinline__ u32 packh2(float a, float b) {
  f16x2 p = {(f16)a, (f16)b};
  return __builtin_bit_cast(u32, p);
}
static __device__ __forceinline__ u16 f16b(float a) { HU u; u.h = (f16)a; return u.b; }
static __device__ __forceinline__ f16x2 ash2(u32 w) { return __builtin_bit_cast(f16x2, w); }

#if __has_builtin(__builtin_amdgcn_fdot2)
#define FDOT2(a, b, c) __builtin_amdgcn_fdot2((a), (b), (c), false)
#else
#define FDOT2(a, b, c) \
  fmaf((float)(a)[0], (float)(b)[0], fmaf((float)(a)[1], (float)(b)[1], (c)))
#endif

__global__ __launch_bounds__(256) void prep(
    const float* __restrict__ W1, const float* __restrict__ b1,
    const float* __restrict__ W2, const float* __restrict__ Wc) {
  const int t = blockIdx.x * 256 + threadIdx.x;  // 0..16383
  if ((t & 1) == 0) {  // h = t&63 even
    const int d = t >> 6, j = (t & 63) >> 1;
    const int idx = d * 32 + j;
    g_Wp[idx]  = packh2(W1[t], W1[t + 1]);
    g_Bp[idx]  = packh2(b1[t], b1[t + 1]);
    g_W2p[idx] = packh2(W2[t], W2[t + 1]);
  }
  const int i4 = t * 4;  // 65536 Wc elements, 4/thread
  const f32x4 v = *reinterpret_cast<const f32x4*>(Wc + i4);
  u16x4 s;
#pragma unroll
  for (int q = 0; q < 4; ++q) s[q] = f16b(v[q]);
  *reinterpret_cast<u16x4*>(g_Wch + i4) = s;
}

// ---- phase 1: u[b][d] for d in [d0,d0+16). Weights wave-uniform (SGPR). ----
__global__ __launch_bounds__(256) void kan_p1(const float* __restrict__ x,
                                              const float* __restrict__ b2) {
  const int tid = threadIdx.x;
  const int b   = (blockIdx.x >> 4) * 256 + tid;   // batch row (lane-consecutive)
  const int d0  = (blockIdx.x & 15) * 16;          // block-uniform d-chunk

  f32x4 xr[4];
#pragma unroll
  for (int c = 0; c < 4; ++c)
    xr[c] = *reinterpret_cast<const f32x4*>(x + b * D_N + d0 + c * 4);

  float uo[16];
#pragma unroll
  for (int c = 0; c < 4; ++c) {
#pragma unroll
    for (int e = 0; e < 4; ++e) {
      const int dd = c * 4 + e;
      const int d  = d0 + dd;                      // uniform
      const f16 hx = (f16)xr[c][e];
      const f16x2 xx = {hx, hx};
      float acc = 0.f;
      const u32* __restrict__ wp  = g_Wp  + d * 32;
      const u32* __restrict__ bp  = g_Bp  + d * 32;
      const u32* __restrict__ w2p = g_W2p + d * 32;
#pragma unroll
      for (int j = 0; j < 32; ++j) {
        f16x2 tv = __builtin_elementwise_fma(xx, ash2(wp[j]), ash2(bp[j]));
        tv = __builtin_elementwise_max(tv, (f16x2){(f16)0.f, (f16)0.f});
        acc = FDOT2(tv, ash2(w2p[j]), acc);        // f32 accumulate
      }
      uo[dd] = acc + b2[d];
    }
  }

  // two 16B fragment-ordered chunks: coalesced (consecutive lanes -> +16B)
  const int base = ((b >> 4) * 32 + (d0 >> 3)) * 128 + (b & 15) * 8;  // u16 units
#pragma unroll
  for (int half = 0; half < 2; ++half) {
    union { u16 h[8]; uint4v v; } pk;
#pragma unroll
    for (int e = 0; e < 8; ++e) pk.h[e] = f16b(uo[half * 8 + e]);
    *reinterpret_cast<uint4v*>(g_Uf + base + half * 128) = pk.v;
  }
}

// ---- phase 2: out = u @ Wc^T + bc. Zero LDS, zero barriers. ----
__global__ __launch_bounds__(256) void kan_p2(const float* __restrict__ bc,
                                              float* __restrict__ out) {
  const int t    = threadIdx.x;
  const int wv   = t >> 6, dl = t & 63;
  const int mt   = blockIdx.x;        // 16-row M tile
  const int n0   = wv * 64;
  const int mrow = dl & 15;
  const int kgrp = dl >> 4;
  const int b0   = mt * 16;

  f32x4 acc2[4];
#pragma unroll
  for (int j = 0; j < 4; ++j) acc2[j] = (f32x4)(0.f);

#pragma unroll
  for (int ks = 0; ks < 8; ++ks) {
    const int k0 = ks * 32 + kgrp * 8;
    const f16x8 afrag = *reinterpret_cast<const f16x8*>(
        g_Uf + (mt * 32 + ks * 4 + kgrp) * 128 + mrow * 8);  // coalesced 16B
#pragma unroll
    for (int j = 0; j < 4; ++j) {
      const f16x8 bfrag = *reinterpret_cast<const f16x8*>(
          g_Wch + (n0 + j * 16 + mrow) * D_N + k0);          // L2-resident
      acc2[j] = __builtin_amdgcn_mfma_f32_16x16x32_f16(afrag, bfrag, acc2[j],
                                                       0, 0, 0);
    }
  }

  // epilogue: C/D map col=lane&15, row=4*(lane>>4)+q (m89-verified)
#pragma unroll
  for (int j = 0; j < 4; ++j) {
    const int colg = n0 + j * 16 + mrow;
    const float bcv = bc[colg];
#pragma unroll
    for (int q = 0; q < 4; ++q) {
      const int rowg = b0 + kgrp * 4 + q;
      out[rowg * O_N + colg] = acc2[j][q] + bcv;
    }
  }
}

extern "C" void kernel_launch(void* const* d_in, const int* in_sizes, int n_in,
                              void* d_out, int out_size, void* d_ws, size_t ws_size,
                              hipStream_t stream) {
  const float* x  = (const float*)d_in[0];
  const float* W1 = (const float*)d_in[1];
  const float* b1 = (const float*)d_in[2];
  const float* W2 = (const float*)d_in[3];
  const float* b2 = (const float*)d_in[4];
  const float* Wc = (const float*)d_in[5];
  const float* bc = (const float*)d_in[6];
  float* out = (float*)d_out;

  prep<<<dim3(D_N * H_N / 256), dim3(256), 0, stream>>>(W1, b1, W2, Wc);
  kan_p1<<<dim3((B_N / 256) * (D_N / 16)), dim3(256), 0, stream>>>(x, b2);
  kan_p2<<<dim3(B_N / 16), dim3(256), 0, stream>>>(bc, out);
}